// Round 9
// baseline (198.008 us; speedup 1.0000x reference)
//
#include <hip/hip_runtime.h>
#include <stdint.h>

#define IN_F   4096
#define OUT_F  11008
#define BATCH  8
#define RPW    2          // output rows per wave
#define WAVES  4          // waves per block
#define RPB    (RPW*WAVES)
#define CHUNK  256        // i-values per chunk (64 lanes * 4 elements)
#define NCHUNK (IN_F/CHUNK)   // 16

#define SBAR() __builtin_amdgcn_sched_barrier(0)

__device__ __forceinline__ float qins_decode(int code, int sgn, float d0, float d1) {
    // |w| = exp2(d0 + code*d1); sign bit straight from the int32 sign (+1 / -1)
    const float e = __builtin_amdgcn_exp2f(fmaf((float)code, d1, d0));
    const uint32_t m = ((uint32_t)sgn) & 0x80000000u;
    return __uint_as_float(__float_as_uint(e) ^ m);
}

// Issue one chunk's 12 loads (2 code rows + 2 sign rows + 8 x rows) as one
// burst. sched_barrier(0) fences around the call keep the scheduler from
// sinking these next to their uses (the R2/R5/R6 failure mode, VGPR=60).
#define LOADCHUNK(cc, gg, xx, IPOS)                                          \
    do {                                                                     \
        const int _ip = (IPOS) + ii0;                                        \
        (cc)[0] = *reinterpret_cast<const int4*>(stored + row0 + _ip);       \
        (cc)[1] = *reinterpret_cast<const int4*>(stored + row1 + _ip);       \
        (gg)[0] = *reinterpret_cast<const int4*>(sign + row0 + _ip);         \
        (gg)[1] = *reinterpret_cast<const int4*>(sign + row1 + _ip);         \
        _Pragma("unroll")                                                    \
        for (int b = 0; b < BATCH; ++b)                                      \
            (xx)[b] = *reinterpret_cast<const float4*>(x + b * IN_F + _ip);  \
    } while (0)

// Pure-register compute: decode 8 weights/lane + 64 FMAs (all indices static)
#define COMPUTE(cc, gg, xx)                                                  \
    do {                                                                     \
        float w[RPW][4];                                                     \
        _Pragma("unroll")                                                    \
        for (int r = 0; r < RPW; ++r) {                                      \
            w[r][0] = qins_decode((cc)[r].x, (gg)[r].x, d0, d1);             \
            w[r][1] = qins_decode((cc)[r].y, (gg)[r].y, d0, d1);             \
            w[r][2] = qins_decode((cc)[r].z, (gg)[r].z, d0, d1);             \
            w[r][3] = qins_decode((cc)[r].w, (gg)[r].w, d0, d1);             \
        }                                                                    \
        _Pragma("unroll")                                                    \
        for (int b = 0; b < BATCH; ++b) {                                    \
            _Pragma("unroll")                                                \
            for (int r = 0; r < RPW; ++r) {                                  \
                float a = acc[r][b];                                         \
                a = fmaf(w[r][0], (xx)[b].x, a);                             \
                a = fmaf(w[r][1], (xx)[b].y, a);                             \
                a = fmaf(w[r][2], (xx)[b].z, a);                             \
                a = fmaf(w[r][3], (xx)[b].w, a);                             \
                acc[r][b] = a;                                               \
            }                                                                \
        }                                                                    \
    } while (0)

__global__ __launch_bounds__(WAVES*64, 3)
void qins_linear_kernel(const float* __restrict__ x,
                        const int*   __restrict__ stored,
                        const int*   __restrict__ sign,
                        const float* __restrict__ log_min,
                        const float* __restrict__ log_max,
                        const float* __restrict__ bias,
                        float* __restrict__ out)
{
    const int lane = threadIdx.x & 63;
    const int wave = threadIdx.x >> 6;
    const int o0   = blockIdx.x * RPB + wave * RPW;

    const float lmin = log_min[0];
    const float lmax = log_max[0];
    const float L2E  = 1.44269504088896340736f;
    // log2(|w|) = d0 + code*d1
    const float d1 = -(lmax - lmin) * (L2E / 254.0f);
    const float d0 = (lmin + (lmax - lmin) * (255.0f / 254.0f)) * L2E;

    float acc[RPW][BATCH];
#pragma unroll
    for (int r = 0; r < RPW; ++r)
#pragma unroll
        for (int b = 0; b < BATCH; ++b) acc[r][b] = 0.0f;

    const int ii0  = lane * 4;
    const int row0 = (o0 + 0) * IN_F;
    const int row1 = (o0 + 1) * IN_F;

    // 2-chunk register double-buffer, protected by sched_barrier fences
    int4   cA[RPW], gA[RPW], cB[RPW], gB[RPW];
    float4 xA[BATCH], xB[BATCH];

    LOADCHUNK(cA, gA, xA, 0);            // chunk 0 in flight
    LOADCHUNK(cB, gB, xB, CHUNK);        // chunk 1 in flight (24 outstanding)
    SBAR();

#pragma unroll 1
    for (int k = 0; k < NCHUNK - 2; k += 2) {
        COMPUTE(cA, gA, xA);             // chunk k   (waits to vmcnt(12))
        SBAR();
        LOADCHUNK(cA, gA, xA, (k + 2) * CHUNK);   // refill slot A -> chunk k+2
        SBAR();
        COMPUTE(cB, gB, xB);             // chunk k+1 (waits to vmcnt(12))
        SBAR();
        LOADCHUNK(cB, gB, xB, (k + 3) * CHUNK);   // refill slot B -> chunk k+3
        SBAR();
    }
    COMPUTE(cA, gA, xA);                 // chunk 14
    COMPUTE(cB, gB, xB);                 // chunk 15

    // full-wave butterfly reduction for the 16 (row,batch) partials
#pragma unroll
    for (int r = 0; r < RPW; ++r)
#pragma unroll
        for (int b = 0; b < BATCH; ++b) {
            float v = acc[r][b];
#pragma unroll
            for (int s = 32; s >= 1; s >>= 1)
                v += __shfl_xor(v, s, 64);
            acc[r][b] = v;
        }

    if (lane == 0) {
#pragma unroll
        for (int r = 0; r < RPW; ++r) {
            const float bv = bias[o0 + r];
#pragma unroll
            for (int b = 0; b < BATCH; ++b)
                out[(size_t)b * OUT_F + o0 + r] = acc[r][b] + bv;
        }
    }
}

extern "C" void kernel_launch(void* const* d_in, const int* in_sizes, int n_in,
                              void* d_out, int out_size, void* d_ws, size_t ws_size,
                              hipStream_t stream)
{
    const float* x      = (const float*)d_in[0];
    const int*   stored = (const int*)d_in[1];
    const int*   sign   = (const int*)d_in[2];
    const float* lmin   = (const float*)d_in[3];
    const float* lmax   = (const float*)d_in[4];
    const float* bias   = (const float*)d_in[5];
    float* out = (float*)d_out;

    dim3 grid(OUT_F / RPB), block(WAVES * 64);
    qins_linear_kernel<<<grid, block, 0, stream>>>(x, stored, sign, lmin, lmax, bias, out);
}

// Round 10
// 80.825 us; speedup vs baseline: 2.4498x; 2.4498x over previous
//
#include <hip/hip_runtime.h>
#include <stdint.h>

#define IN_F   4096
#define OUT_F  11008
#define BATCH  8
#define RPW    4              // output rows per wave (1 wave per block)
#define CHUNK  256            // i-values per chunk (64 lanes * 4 ints per DMA)
#define NCHUNK (IN_F/CHUNK)   // 16
#define NSTREAM (2*RPW + BATCH)   // 16 streams of 1 KB per chunk slot

typedef __attribute__((address_space(1))) const uint32_t* gas_t;
typedef __attribute__((address_space(3))) uint32_t* las_t;

// async global->LDS DMA, 16 B/lane: no VGPR destination, regalloc-proof
#define DMA16(gsrc, ldst) \
    __builtin_amdgcn_global_load_lds((gas_t)(gsrc), (las_t)(ldst), 16, 0, 0)

// counted wait + scheduling fence (rule #18)
#define VWAIT(N)                                                             \
    do {                                                                     \
        asm volatile("s_waitcnt vmcnt(" #N ")" ::: "memory");                \
        __builtin_amdgcn_sched_barrier(0);                                   \
    } while (0)
#define SBAR() __builtin_amdgcn_sched_barrier(0)

__device__ __forceinline__ float qins_decode(int code, int sgn, float d0, float d1) {
    // |w| = exp2(d0 + code*d1); sign bit straight from the int32 sign (+1 / -1)
    const float e = __builtin_amdgcn_exp2f(fmaf((float)code, d1, d0));
    const uint32_t m = ((uint32_t)sgn) & 0x80000000u;
    return __uint_as_float(__float_as_uint(e) ^ m);
}

// issue one chunk's 16 DMAs into slot T (4 KB stored + 4 KB sign + 8 KB x)
#define ISSUE(T, K)                                                          \
    do {                                                                     \
        const int _ip = (K) * CHUNK + il;                                    \
        _Pragma("unroll")                                                    \
        for (int r = 0; r < RPW; ++r)                                        \
            DMA16(stored + (o0 + r) * IN_F + _ip, &lds[T][r][0]);            \
        _Pragma("unroll")                                                    \
        for (int r = 0; r < RPW; ++r)                                        \
            DMA16(sign + (o0 + r) * IN_F + _ip, &lds[T][RPW + r][0]);        \
        _Pragma("unroll")                                                    \
        for (int b = 0; b < BATCH; ++b)                                      \
            DMA16((const uint32_t*)x + b * IN_F + _ip,                       \
                  &lds[T][2 * RPW + b][0]);                                  \
    } while (0)

// consume slot T: ds_read back, decode 16 weights/lane, 128 FMAs
#define COMPUTE(T)                                                           \
    do {                                                                     \
        int4 c[RPW], g[RPW];                                                 \
        _Pragma("unroll")                                                    \
        for (int r = 0; r < RPW; ++r) {                                      \
            c[r] = *reinterpret_cast<const int4*>(&lds[T][r][il]);           \
            g[r] = *reinterpret_cast<const int4*>(&lds[T][RPW + r][il]);     \
        }                                                                    \
        float4 xv[BATCH];                                                    \
        _Pragma("unroll")                                                    \
        for (int b = 0; b < BATCH; ++b)                                      \
            xv[b] = *reinterpret_cast<const float4*>(&lds[T][2 * RPW + b][il]); \
        float w[RPW][4];                                                     \
        _Pragma("unroll")                                                    \
        for (int r = 0; r < RPW; ++r) {                                      \
            w[r][0] = qins_decode(c[r].x, g[r].x, d0, d1);                   \
            w[r][1] = qins_decode(c[r].y, g[r].y, d0, d1);                   \
            w[r][2] = qins_decode(c[r].z, g[r].z, d0, d1);                   \
            w[r][3] = qins_decode(c[r].w, g[r].w, d0, d1);                   \
        }                                                                    \
        _Pragma("unroll")                                                    \
        for (int b = 0; b < BATCH; ++b) {                                    \
            _Pragma("unroll")                                                \
            for (int r = 0; r < RPW; ++r) {                                  \
                float a = acc[r][b];                                         \
                a = fmaf(w[r][0], xv[b].x, a);                               \
                a = fmaf(w[r][1], xv[b].y, a);                               \
                a = fmaf(w[r][2], xv[b].z, a);                               \
                a = fmaf(w[r][3], xv[b].w, a);                               \
                acc[r][b] = a;                                               \
            }                                                                \
        }                                                                    \
    } while (0)

__global__ __launch_bounds__(64, 2)
void qins_linear_kernel(const float* __restrict__ x,
                        const uint32_t* __restrict__ stored,
                        const uint32_t* __restrict__ sign,
                        const float* __restrict__ log_min,
                        const float* __restrict__ log_max,
                        const float* __restrict__ bias,
                        float* __restrict__ out)
{
    // [slot][stream][ints]: 2 x 16 x 1 KB = 32 KB, per-wave private (1 wave/block)
    __shared__ int lds[2][NSTREAM][CHUNK];

    const int lane = threadIdx.x;          // 64 threads = 1 wave
    const int o0   = blockIdx.x * RPW;
    const int il   = lane * 4;             // int index of this lane's 16 B

    const float lmin = log_min[0];
    const float lmax = log_max[0];
    const float L2E  = 1.44269504088896340736f;
    // log2(|w|) = d0 + code*d1
    const float d1 = -(lmax - lmin) * (L2E / 254.0f);
    const float d0 = (lmin + (lmax - lmin) * (255.0f / 254.0f)) * L2E;

    float acc[RPW][BATCH];
#pragma unroll
    for (int r = 0; r < RPW; ++r)
#pragma unroll
        for (int b = 0; b < BATCH; ++b) acc[r][b] = 0.0f;

    // prologue: chunks 0 and 1 in flight (32 outstanding DMAs)
    ISSUE(0, 0);
    ISSUE(1, 1);
    SBAR();

#pragma unroll 1
    for (int k = 0; k < NCHUNK - 2; k += 2) {
        VWAIT(16);                 // chunk k ready; chunk k+1's 16 stay in flight
        COMPUTE(0);
        SBAR();
        ISSUE(0, k + 2);           // refill slot 0 -> chunk k+2
        SBAR();
        VWAIT(16);                 // chunk k+1 ready; chunk k+2 in flight
        COMPUTE(1);
        SBAR();
        ISSUE(1, k + 3);           // refill slot 1 -> chunk k+3
        SBAR();
    }
    VWAIT(16);
    COMPUTE(0);                    // chunk 14
    VWAIT(0);
    COMPUTE(1);                    // chunk 15

    // full-wave butterfly reduction for the 32 (row,batch) partials
#pragma unroll
    for (int r = 0; r < RPW; ++r)
#pragma unroll
        for (int b = 0; b < BATCH; ++b) {
            float v = acc[r][b];
#pragma unroll
            for (int s = 32; s >= 1; s >>= 1)
                v += __shfl_xor(v, s, 64);
            acc[r][b] = v;
        }

    if (lane == 0) {
#pragma unroll
        for (int r = 0; r < RPW; ++r) {
            const float bv = bias[o0 + r];
#pragma unroll
            for (int b = 0; b < BATCH; ++b)
                out[(size_t)b * OUT_F + o0 + r] = acc[r][b] + bv;
        }
    }
}

extern "C" void kernel_launch(void* const* d_in, const int* in_sizes, int n_in,
                              void* d_out, int out_size, void* d_ws, size_t ws_size,
                              hipStream_t stream)
{
    const float*    x      = (const float*)d_in[0];
    const uint32_t* stored = (const uint32_t*)d_in[1];
    const uint32_t* sign   = (const uint32_t*)d_in[2];
    const float*    lmin   = (const float*)d_in[3];
    const float*    lmax   = (const float*)d_in[4];
    const float*    bias   = (const float*)d_in[5];
    float* out = (float*)d_out;

    dim3 grid(OUT_F / RPW), block(64);
    qins_linear_kernel<<<grid, block, 0, stream>>>(x, stored, sign, lmin, lmax, bias, out);
}